// Round 1
// baseline (501.863 us; speedup 1.0000x reference)
//
#include <hip/hip_runtime.h>

#define DDIM 2048
#define SLEN 2048
#define BSZ 4
#define NTOK (BSZ*SLEN)        // 8192
#define RANK 160
#define SROWS 66               // 2 + HEAD_SIZE
#define OUT_MAIN ((size_t)NTOK*5*DDIM)   // 83,886,080 floats
#define STATE_N (BSZ*SROWS*DDIM)         // 540,672 floats

typedef __bf16 bf16x8 __attribute__((ext_vector_type(8)));
typedef float  f32x4  __attribute__((ext_vector_type(4)));
typedef unsigned short us8 __attribute__((ext_vector_type(8)));

__device__ __forceinline__ unsigned short f2bf(float f) {
    unsigned b = __float_as_uint(f);
    return (unsigned short)((b + 0x7fffu + ((b >> 16) & 1u)) >> 16);  // RNE
}

// ---- new_state: copy state, overwrite row i1 with x[:, S-1, :]  (fp32) ----
__global__ void k_state(const float* __restrict__ x,
                        const float* __restrict__ state,
                        const int* __restrict__ pi,
                        float* __restrict__ out_state) {
    int t = blockIdx.x * blockDim.x + threadIdx.x;
    int idx = t * 4;
    if (idx >= STATE_N) return;
    int i1 = 66 * pi[0] + 1;
    int b   = idx / (SROWS * DDIM);
    int rem = idx - b * (SROWS * DDIM);
    int row = rem / DDIM;
    int d   = rem - row * DDIM;
    f32x4 v;
    if (row == i1) v = *(const f32x4*)(x + ((size_t)(b * SLEN + SLEN - 1)) * DDIM + d);
    else           v = *(const f32x4*)(state + idx);
    *(f32x4*)(out_state + idx) = v;
}

// ---- transpose+convert W1 [2048,160] f32 -> W1T [160,2048] bf16 ----
__global__ void k_t_w1(const float* __restrict__ w1,
                       unsigned short* __restrict__ w1t) {
    int o = blockIdx.x * blockDim.x + threadIdx.x;  // o = n*2048 + k
    if (o >= RANK * DDIM) return;
    int n = o >> 11;
    int k = o & (DDIM - 1);
    w1t[o] = f2bf(w1[k * RANK + n]);
}

// ---- transpose+convert W2 [5,32,2048] f32 -> W2T [5,2048,32] bf16 ----
__global__ void k_t_w2(const float* __restrict__ w2,
                       unsigned short* __restrict__ w2t) {
    int o = blockIdx.x * blockDim.x + threadIdx.x;  // o = (f*2048+d)*32 + k
    if (o >= 5 * DDIM * 32) return;
    int k  = o & 31;
    int fd = o >> 5;
    int d  = fd & (DDIM - 1);
    int f  = fd >> 11;
    w2t[o] = f2bf(w2[(f * 32 + k) * DDIM + d]);
}

// ---- GEMM1 fused: xxx = tanh((x + sx*tmx) @ W1), M=8192 K=2048 N=160 ----
// Block: 32 tokens x 160 n. xw computed on the fly (fp32 in, bf16 LDS tile).
__global__ __launch_bounds__(256) void k_gemm1f(
        const float* __restrict__ x,
        const float* __restrict__ state,
        const float* __restrict__ tmx,
        const unsigned short* __restrict__ w1t,
        const int* __restrict__ pi,
        unsigned short* __restrict__ xxx) {
    __shared__ unsigned short sxw[32 * 88];   // bf16, row stride 88 (pad: 40->44 words)
    int tid  = threadIdx.x;
    int w    = tid >> 6, lane = tid & 63;
    int q    = lane >> 4, nl = lane & 15;
    int msub = w & 1, nh = w >> 1;            // rows msub*16.., cols nh*80..
    int m0   = blockIdx.x * 32;
    int b    = m0 >> 11;
    int i1   = 66 * pi[0] + 1;

    // staging assignment: thread -> (row 0..31, col-vec of 8 floats)
    int srow = tid >> 3;
    int scol = (tid & 7) * 8;
    int m    = m0 + srow;
    int s    = m & (SLEN - 1);
    const float* xrow = x + (size_t)m * DDIM;
    const float* prow = (s == 0)
        ? (state + (size_t)(b * SROWS + i1) * DDIM)
        : (x + (size_t)(m - 1) * DDIM);

    f32x4 acc[5];
    #pragma unroll
    for (int t = 0; t < 5; t++) acc[t] = (f32x4){0.f, 0.f, 0.f, 0.f};

    for (int k0 = 0; k0 < DDIM; k0 += 64) {
        // stage xw tile [32 x 64] as bf16
        f32x4 xa = *(const f32x4*)(xrow + k0 + scol);
        f32x4 xb = *(const f32x4*)(xrow + k0 + scol + 4);
        f32x4 pa = *(const f32x4*)(prow + k0 + scol);
        f32x4 pb = *(const f32x4*)(prow + k0 + scol + 4);
        f32x4 ta = *(const f32x4*)(tmx  + k0 + scol);
        f32x4 tb = *(const f32x4*)(tmx  + k0 + scol + 4);
        us8 o;
        #pragma unroll
        for (int j = 0; j < 4; j++) {
            o[j]     = f2bf(xa[j] + (pa[j] - xa[j]) * ta[j]);
            o[j + 4] = f2bf(xb[j] + (pb[j] - xb[j]) * tb[j]);
        }
        *(us8*)(sxw + srow * 88 + scol) = o;
        __syncthreads();

        #pragma unroll
        for (int kk = 0; kk < 64; kk += 32) {
            bf16x8 a = *(const bf16x8*)(sxw + (msub * 16 + nl) * 88 + kk + q * 8);
            #pragma unroll
            for (int t = 0; t < 5; t++) {
                bf16x8 bb = *(const bf16x8*)(w1t + (size_t)(nh * 80 + t * 16 + nl) * DDIM
                                             + k0 + kk + q * 8);
                acc[t] = __builtin_amdgcn_mfma_f32_16x16x32_bf16(a, bb, acc[t], 0, 0, 0);
            }
        }
        __syncthreads();
    }

    #pragma unroll
    for (int t = 0; t < 5; t++)
        #pragma unroll
        for (int r = 0; r < 4; r++) {
            int mm = m0 + msub * 16 + q * 4 + r;     // C row = q*4+r
            int nn = nh * 80 + t * 16 + nl;          // C col = nl
            xxx[mm * RANK + nn] = f2bf(tanhf(acc[t][r]));
        }
}

// ---- GEMM2 (K=32, one MFMA per tile) + epilogue, fp32 out ----
// block: 16 tokens x 128 d x 5 f
__global__ __launch_bounds__(256) void k_gemm2_out(
        const unsigned short* __restrict__ xxx,
        const unsigned short* __restrict__ w2t,
        const float* __restrict__ x,
        const float* __restrict__ state,
        const float* __restrict__ mk,
        const float* __restrict__ mw,
        const float* __restrict__ mv,
        const float* __restrict__ mr,
        const float* __restrict__ mg,
        const int* __restrict__ pi,
        float* __restrict__ out) {
    __shared__ float res[5 * 16 * 132];   // row stride 132 words
    int tid = threadIdx.x;
    int w = tid >> 6, lane = tid & 63;
    int q = lane >> 4, nl = lane & 15;
    int tokTile = blockIdx.x >> 4;
    int dTile   = blockIdx.x & 15;
    int m0 = tokTile * 16;
    int d0 = dTile * 128;

    for (int t = w; t < 40; t += 4) {
        int f = t >> 3, dsub = t & 7;
        bf16x8 a = *(const bf16x8*)(xxx + (size_t)(m0 + nl) * RANK + f * 32 + q * 8);
        bf16x8 b = *(const bf16x8*)(w2t + ((size_t)(f * DDIM) + d0 + dsub * 16 + nl) * 32 + q * 8);
        f32x4 acc = (f32x4){0.f, 0.f, 0.f, 0.f};
        acc = __builtin_amdgcn_mfma_f32_16x16x32_bf16(a, b, acc, 0, 0, 0);
        #pragma unroll
        for (int r = 0; r < 4; r++)
            res[(f * 16 + q * 4 + r) * 132 + dsub * 16 + nl] = acc[r];
    }
    __syncthreads();

    int i1 = 66 * pi[0] + 1;
    const float* maas[5] = {mk, mw, mv, mr, mg};
    int b     = m0 >> 11;
    int sbase = m0 & (SLEN - 1);
    #pragma unroll
    for (int it = 0; it < 10; it++) {
        int g   = it * 256 + tid;       // 2560 vec4-groups = 16 tok x 5 f x 32 dv
        int tok = g / 160;
        int r2  = g - tok * 160;
        int f   = r2 >> 5;
        int dv  = (r2 & 31) * 4;
        int s   = sbase + tok;
        int d   = d0 + dv;
        size_t xoff = ((size_t)(b * SLEN + s)) * DDIM + d;
        f32x4 xv = *(const f32x4*)(x + xoff);
        f32x4 pv;
        if (s == 0) pv = *(const f32x4*)(state + ((size_t)(b * SROWS + i1)) * DDIM + d);
        else        pv = *(const f32x4*)(x + xoff - DDIM);
        f32x4 mvv = *(const f32x4*)(maas[f] + d);
        f32x4 rr  = *(const f32x4*)&res[(f * 16 + tok) * 132 + dv];
        f32x4 o;
        #pragma unroll
        for (int j = 0; j < 4; j++) {
            float xf = xv[j];
            float sx = pv[j] - xf;
            o[j] = xf + sx * (mvv[j] + rr[j]);
        }
        *(f32x4*)(out + ((size_t)((b * SLEN + s) * 5 + f)) * DDIM + d) = o;
    }
}

extern "C" void kernel_launch(void* const* d_in, const int* in_sizes, int n_in,
                              void* d_out, int out_size, void* d_ws, size_t ws_size,
                              hipStream_t stream) {
    const float* x   = (const float*)d_in[0];
    const float* st  = (const float*)d_in[1];
    const float* tmx = (const float*)d_in[2];
    const float* w1  = (const float*)d_in[3];
    const float* w2  = (const float*)d_in[4];
    const float* mk  = (const float*)d_in[5];
    const float* mw  = (const float*)d_in[6];
    const float* mv  = (const float*)d_in[7];
    const float* mr  = (const float*)d_in[8];
    const float* mg  = (const float*)d_in[9];
    const int* pi    = (const int*)d_in[10];
    float* out = (float*)d_out;

    // ws usage: 3,932,160 bytes total
    char* ws = (char*)d_ws;
    unsigned short* xxx = (unsigned short*)(ws);                    // 2,621,440 B
    unsigned short* w1t = (unsigned short*)(ws + 2621440);          //   655,360 B
    unsigned short* w2t = (unsigned short*)(ws + 2621440 + 655360); //   655,360 B

    k_state<<<528, 256, 0, stream>>>(x, st, pi, out + OUT_MAIN);
    k_t_w1<<<1280, 256, 0, stream>>>(w1, w1t);
    k_t_w2<<<1280, 256, 0, stream>>>(w2, w2t);
    k_gemm1f<<<256, 256, 0, stream>>>(x, st, tmx, w1t, pi, xxx);
    k_gemm2_out<<<8192, 256, 0, stream>>>(xxx, w2t, x, st, mk, mw, mv, mr, mg, pi, out);
}

// Round 2
// 459.640 us; speedup vs baseline: 1.0919x; 1.0919x over previous
//
#include <hip/hip_runtime.h>

#define DDIM 2048
#define SLEN 2048
#define BSZ 4
#define NTOK (BSZ*SLEN)        // 8192
#define RANK 160
#define SROWS 66               // 2 + HEAD_SIZE
#define OUT_MAIN ((size_t)NTOK*5*DDIM)   // 83,886,080 floats
#define STATE_N (BSZ*SROWS*DDIM)         // 540,672 floats

typedef __bf16 bf16x8 __attribute__((ext_vector_type(8)));
typedef float  f32x4  __attribute__((ext_vector_type(4)));
typedef unsigned short us8 __attribute__((ext_vector_type(8)));
typedef unsigned short us4 __attribute__((ext_vector_type(4)));

__device__ __forceinline__ unsigned short f2bf(float f) {
    unsigned b = __float_as_uint(f);
    return (unsigned short)((b + 0x7fffu + ((b >> 16) & 1u)) >> 16);  // RNE
}

// ---- prep: blocks [0,320) transpose W1, [320,640) transpose W2, [640,1168) state copy
__global__ __launch_bounds__(256) void k_prep(
        const float* __restrict__ x,
        const float* __restrict__ state,
        const int* __restrict__ pi,
        const float* __restrict__ w1,
        const float* __restrict__ w2,
        float* __restrict__ out_state,
        unsigned short* __restrict__ w1t,
        unsigned short* __restrict__ w2t) {
    __shared__ float t[32 * 33];
    int bid = blockIdx.x, tid = threadIdx.x;
    if (bid < 320) {
        // W1 [2048,160] f32 -> W1T [160,2048] bf16, 32x32 LDS tile
        int kt = bid / 5;
        int k0 = kt * 32, n0 = (bid - kt * 5) * 32;
        int rr = tid >> 3, cc = (tid & 7) * 4;
        f32x4 v = *(const f32x4*)(w1 + (size_t)(k0 + rr) * RANK + n0 + cc);
        #pragma unroll
        for (int j = 0; j < 4; j++) t[(cc + j) * 33 + rr] = v[j];  // t[n_local][k_local]
        __syncthreads();
        us4 o;
        #pragma unroll
        for (int j = 0; j < 4; j++) o[j] = f2bf(t[rr * 33 + cc + j]);
        *(us4*)(w1t + (size_t)(n0 + rr) * DDIM + k0 + cc) = o;
    } else if (bid < 640) {
        // W2 [5,32,2048] f32 -> W2T [5,2048,32] bf16, 32x32 LDS tile per f
        int b2 = bid - 320;
        int f = b2 >> 6, d0 = (b2 & 63) * 32;
        int rr = tid >> 3, cc = (tid & 7) * 4;       // rr = k_local, cc = d_local
        f32x4 v = *(const f32x4*)(w2 + (size_t)(f * 32 + rr) * DDIM + d0 + cc);
        #pragma unroll
        for (int j = 0; j < 4; j++) t[(cc + j) * 33 + rr] = v[j];  // t[d_local][k_local]
        __syncthreads();
        us4 o;
        #pragma unroll
        for (int j = 0; j < 4; j++) o[j] = f2bf(t[rr * 33 + cc + j]);  // rr = d_local now
        *(us4*)(w2t + ((size_t)(f * DDIM) + d0 + rr) * 32 + cc) = o;
    } else {
        // state copy, overwrite row i1 with x[:, S-1, :]
        int idx = ((bid - 640) * 256 + tid) * 4;     // STATE_N = 528*256*4 exactly
        int i1 = 66 * pi[0] + 1;
        int b   = idx / (SROWS * DDIM);
        int rem = idx - b * (SROWS * DDIM);
        int row = rem / DDIM;
        int d   = rem - row * DDIM;
        f32x4 v;
        if (row == i1) v = *(const f32x4*)(x + ((size_t)(b * SLEN + SLEN - 1)) * DDIM + d);
        else           v = *(const f32x4*)(state + idx);
        *(f32x4*)(out_state + idx) = v;
    }
}

// ---- GEMM1 fused: xxx = tanh((x + sx*tmx) @ W1), M=8192 K=2048 N=160 ----
// 16-token tile, 640 threads = 10 waves: kh (K-half) x nh (32 cols). 2 blocks/CU.
__global__ __launch_bounds__(640) void k_gemm1f(
        const float* __restrict__ x,
        const float* __restrict__ state,
        const float* __restrict__ tmx,
        const unsigned short* __restrict__ w1t,
        const int* __restrict__ pi,
        unsigned short* __restrict__ xxx) {
    __shared__ unsigned short sxw[16 * 136];   // bf16 [16 tok][128 K], stride 136
    __shared__ float red[10 * 16 * 17];        // K-half partials [10 tiles][16r][16c+pad]
    int tid  = threadIdx.x;
    int w    = tid >> 6, lane = tid & 63;
    int q    = lane >> 4, nl = lane & 15;
    int kh   = (w >= 5) ? 1 : 0;
    int nh   = kh ? (w - 5) : w;
    int m0   = blockIdx.x * 16;
    int b    = m0 >> 11;
    int i1   = 66 * pi[0] + 1;

    // staging: threads 0..511 stage [16 tok x 128 K] per iteration
    int srow = tid >> 5;
    int scol = (tid & 31) * 4;
    const float* xrow = nullptr;
    const float* prow = nullptr;
    if (tid < 512) {
        int m = m0 + srow;
        int s = m & (SLEN - 1);
        xrow = x + (size_t)m * DDIM;
        prow = (s == 0) ? (state + (size_t)(b * SROWS + i1) * DDIM)
                        : (x + (size_t)(m - 1) * DDIM);
    }

    f32x4 acc[2];
    acc[0] = (f32x4){0.f, 0.f, 0.f, 0.f};
    acc[1] = (f32x4){0.f, 0.f, 0.f, 0.f};

    for (int i = 0; i < 16; i++) {
        if (tid < 512) {
            int gc = i * 128 + scol;
            f32x4 xa = *(const f32x4*)(xrow + gc);
            f32x4 pa = *(const f32x4*)(prow + gc);
            f32x4 ta = *(const f32x4*)(tmx  + gc);
            us4 o;
            #pragma unroll
            for (int j = 0; j < 4; j++)
                o[j] = f2bf(xa[j] + (pa[j] - xa[j]) * ta[j]);
            *(us4*)(sxw + srow * 136 + scol) = o;
        }
        __syncthreads();
        #pragma unroll
        for (int kk = 0; kk < 64; kk += 32) {
            bf16x8 a = *(const bf16x8*)(sxw + nl * 136 + kh * 64 + kk + q * 8);
            #pragma unroll
            for (int t = 0; t < 2; t++) {
                bf16x8 bb = *(const bf16x8*)(w1t + (size_t)(nh * 32 + t * 16 + nl) * DDIM
                                             + i * 128 + kh * 64 + kk + q * 8);
                acc[t] = __builtin_amdgcn_mfma_f32_16x16x32_bf16(a, bb, acc[t], 0, 0, 0);
            }
        }
        __syncthreads();
    }

    if (kh) {
        #pragma unroll
        for (int t = 0; t < 2; t++)
            #pragma unroll
            for (int r = 0; r < 4; r++)
                red[((nh * 2 + t) * 16 + q * 4 + r) * 17 + nl] = acc[t][r];
    }
    __syncthreads();
    if (!kh) {
        #pragma unroll
        for (int t = 0; t < 2; t++)
            #pragma unroll
            for (int r = 0; r < 4; r++) {
                float v = acc[t][r] + red[((nh * 2 + t) * 16 + q * 4 + r) * 17 + nl];
                xxx[(size_t)(m0 + q * 4 + r) * RANK + nh * 32 + t * 16 + nl]
                    = f2bf(tanhf(v));
            }
    }
}

// ---- GEMM2 (K=32, one MFMA per tile) + epilogue, fp32 out ----
// block: 16 tokens x 128 d x 5 f
__global__ __launch_bounds__(256) void k_gemm2_out(
        const unsigned short* __restrict__ xxx,
        const unsigned short* __restrict__ w2t,
        const float* __restrict__ x,
        const float* __restrict__ state,
        const float* __restrict__ mk,
        const float* __restrict__ mw,
        const float* __restrict__ mv,
        const float* __restrict__ mr,
        const float* __restrict__ mg,
        const int* __restrict__ pi,
        float* __restrict__ out) {
    __shared__ float res[5 * 16 * 132];   // row stride 132 words
    int tid = threadIdx.x;
    int w = tid >> 6, lane = tid & 63;
    int q = lane >> 4, nl = lane & 15;
    int tokTile = blockIdx.x >> 4;
    int dTile   = blockIdx.x & 15;
    int m0 = tokTile * 16;
    int d0 = dTile * 128;

    for (int t = w; t < 40; t += 4) {
        int f = t >> 3, dsub = t & 7;
        bf16x8 a = *(const bf16x8*)(xxx + (size_t)(m0 + nl) * RANK + f * 32 + q * 8);
        bf16x8 b = *(const bf16x8*)(w2t + ((size_t)(f * DDIM) + d0 + dsub * 16 + nl) * 32 + q * 8);
        f32x4 acc = (f32x4){0.f, 0.f, 0.f, 0.f};
        acc = __builtin_amdgcn_mfma_f32_16x16x32_bf16(a, b, acc, 0, 0, 0);
        #pragma unroll
        for (int r = 0; r < 4; r++)
            res[(f * 16 + q * 4 + r) * 132 + dsub * 16 + nl] = acc[r];
    }
    __syncthreads();

    int i1 = 66 * pi[0] + 1;
    int b     = m0 >> 11;
    int sbase = m0 & (SLEN - 1);
    #pragma unroll
    for (int half = 0; half < 2; half++) {
        int tt  = half * 256 + tid;     // [0,512): 16 tok x 32 dvec
        int tok = tt >> 5;
        int dv  = (tt & 31) * 4;
        int s   = sbase + tok;
        int d   = d0 + dv;
        size_t xoff = ((size_t)(b * SLEN + s)) * DDIM + d;
        f32x4 xv = *(const f32x4*)(x + xoff);
        f32x4 pv;
        if (s == 0) pv = *(const f32x4*)(state + ((size_t)(b * SROWS + i1)) * DDIM + d);
        else        pv = *(const f32x4*)(x + xoff - DDIM);
        size_t obase = ((size_t)((b * SLEN + s) * 5)) * DDIM + d;
        #pragma unroll
        for (int f = 0; f < 5; f++) {
            const float* maa = (f == 0) ? mk : (f == 1) ? mw : (f == 2) ? mv
                             : (f == 3) ? mr : mg;            // static per unrolled f
            f32x4 mvv = *(const f32x4*)(maa + d);
            f32x4 rr  = *(const f32x4*)&res[(f * 16 + tok) * 132 + dv];
            f32x4 o;
            #pragma unroll
            for (int j = 0; j < 4; j++) {
                float xf = xv[j];
                float sx = pv[j] - xf;
                o[j] = xf + sx * (mvv[j] + rr[j]);
            }
            *(f32x4*)(out + obase + (size_t)f * DDIM) = o;
        }
    }
}

extern "C" void kernel_launch(void* const* d_in, const int* in_sizes, int n_in,
                              void* d_out, int out_size, void* d_ws, size_t ws_size,
                              hipStream_t stream) {
    const float* x   = (const float*)d_in[0];
    const float* st  = (const float*)d_in[1];
    const float* tmx = (const float*)d_in[2];
    const float* w1  = (const float*)d_in[3];
    const float* w2  = (const float*)d_in[4];
    const float* mk  = (const float*)d_in[5];
    const float* mw  = (const float*)d_in[6];
    const float* mv  = (const float*)d_in[7];
    const float* mr  = (const float*)d_in[8];
    const float* mg  = (const float*)d_in[9];
    const int* pi    = (const int*)d_in[10];
    float* out = (float*)d_out;

    // ws usage: 3,932,160 bytes total
    char* ws = (char*)d_ws;
    unsigned short* xxx = (unsigned short*)(ws);                    // 2,621,440 B
    unsigned short* w1t = (unsigned short*)(ws + 2621440);          //   655,360 B
    unsigned short* w2t = (unsigned short*)(ws + 2621440 + 655360); //   655,360 B

    k_prep<<<1168, 256, 0, stream>>>(x, st, pi, w1, w2, out + OUT_MAIN, w1t, w2t);
    k_gemm1f<<<512, 640, 0, stream>>>(x, st, tmx, w1t, pi, xxx);
    k_gemm2_out<<<8192, 256, 0, stream>>>(xxx, w2t, x, st, mk, mw, mv, mr, mg, pi, out);
}